// Round 8
// baseline (221.822 us; speedup 1.0000x reference)
//
#include <hip/hip_runtime.h>
#include <cstddef>

#define EPSF 1e-12f
#define NCB 90
#define NT 30
#define ODIM 256
#define DDIM 8192

typedef unsigned short u16;
typedef __attribute__((ext_vector_type(8))) short short8;
typedef __attribute__((ext_vector_type(4))) float float4v;

__device__ inline u16 f2bf(float f) {
  union { float f; unsigned u; } v; v.f = f;
  unsigned r = v.u + 0x7FFFu + ((v.u >> 16) & 1u);
  return (u16)(r >> 16);
}
__device__ inline float bf2f(u16 h) {
  union { unsigned u; float f; } v; v.u = ((unsigned)h) << 16;
  return v.f;
}

// ---------------------------------------------------------------------------
// K1 (MFMA): R6 structure + XCD-pin swizzle, occupancy 3 (VGPR 84, no spill).
// ---------------------------------------------------------------------------
__global__ __launch_bounds__(256, 3) void k1_assign(
    const float* __restrict__ x,       // [8][128][16][900]
    const float* __restrict__ conv_w,  // [64][128]
    const float* __restrict__ conv_b,  // [64]
    float* __restrict__ P,             // [8][90][64][128]
    float* __restrict__ PA)            // [8][90][64]
{
  __shared__ u16 xtf[4160];        // logits A-frags: F*520 + lane*8 + j
  __shared__ u16 xf[5120];         // P B-frags: ct*640 + (lane>>4)*160 + (lane&15)*8 + j
  __shared__ float As[64 * 33];    // logits -> exp
  __shared__ u16 afr[2048];        // a frags
  __shared__ float Mf[32];
  __shared__ float sm4[128];
  __shared__ float pasum[256];

  const int bx0 = blockIdx.x;
  const int id = (bx0 & 7) * 90 + (bx0 >> 3);   // XCD g (=bx0&7) -> n = g
  const int n = id / NCB, cb = id - n * NCB;
  const int t = threadIdx.x;
  const int lane = t & 63;
  const int w = t >> 6;            // wave 0..3

  const float* xn = x + (size_t)n * 1843200 + cb * 10;

  const int colt = w & 1;
  const int kt0 = w >> 1;
  const float bk0 = conv_b[kt0 * 16 + (lane & 15)];
  const float bk1 = conv_b[(kt0 + 2) * 16 + (lane & 15)];

  short8 w0h[4], w0l[4], w1h[4], w1l[4];
  {
    int kr0 = kt0 * 16 + (lane & 15);
    int kr1 = kr0 + 32;
    int cbase = (lane >> 4) << 3;
#pragma unroll
    for (int cb32 = 0; cb32 < 4; ++cb32) {
      const float* wp0 = conv_w + (size_t)kr0 * 128 + cb32 * 32 + cbase;
      const float* wp1 = conv_w + (size_t)kr1 * 128 + cb32 * 32 + cbase;
      union { u16 u[8]; short8 v; } hh, ll;
#pragma unroll
      for (int j = 0; j < 8; ++j) {
        float fv = wp0[j];
        u16 h = f2bf(fv);
        hh.u[j] = h;
        ll.u[j] = f2bf(fv - bf2f(h));
      }
      w0h[cb32] = hh.v; w0l[cb32] = ll.v;
#pragma unroll
      for (int j = 0; j < 8; ++j) {
        float fv = wp1[j];
        u16 h = f2bf(fv);
        hh.u[j] = h;
        ll.u[j] = f2bf(fv - bf2f(h));
      }
      w1h[cb32] = hh.v; w1l[cb32] = ll.v;
    }
  }

  float4v pacc[8];
#pragma unroll
  for (int i = 0; i < 8; ++i) pacc[i] = (float4v){0.f, 0.f, 0.f, 0.f};
  float pak = 0.f;

  for (int cc = 0; cc < 5; ++cc) {
    __syncthreads();
#pragma unroll
    for (int s = 0; s < 8; ++s) {
      int e2 = t + 256 * s;
      int c = e2 >> 4, p = e2 & 15;
      int cl = 2 * p;
      int g = cc * 32 + cl;
      int h = g / 10, wi = g - 10 * h;
      float2 val = *(const float2*)(xn + (size_t)c * 14400 + h * 900 + wi);
      u16 h0 = f2bf(val.x), h1 = f2bf(val.y);
      int ip = (c >> 4) * 640 + (p >> 2) * 160 + (c & 15) * 8 + (cl & 7);
      ushort2 pr; pr.x = h0; pr.y = h1;
      *(ushort2*)&xf[ip] = pr;
      int F = (p >> 3) * 4 + (c >> 5);
      int L = (((c >> 3) & 3) << 4) + (cl & 15);
      int i0 = F * 520 + L * 8 + (c & 7);
      xtf[i0] = h0;
      xtf[i0 + 8] = h1;
    }
    __syncthreads();

    {
      float4v d0 = (float4v){0.f, 0.f, 0.f, 0.f};
      float4v d1 = (float4v){0.f, 0.f, 0.f, 0.f};
#pragma unroll
      for (int cb32 = 0; cb32 < 4; ++cb32) {
        short8 xa = *(short8*)&xtf[(colt * 4 + cb32) * 520 + lane * 8];
        d0 = __builtin_amdgcn_mfma_f32_16x16x32_bf16(xa, w0h[cb32], d0, 0, 0, 0);
        d0 = __builtin_amdgcn_mfma_f32_16x16x32_bf16(xa, w0l[cb32], d0, 0, 0, 0);
        d1 = __builtin_amdgcn_mfma_f32_16x16x32_bf16(xa, w1h[cb32], d1, 0, 0, 0);
        d1 = __builtin_amdgcn_mfma_f32_16x16x32_bf16(xa, w1l[cb32], d1, 0, 0, 0);
      }
      int colb = colt * 16 + ((lane >> 4) << 2);
      int kr0 = kt0 * 16 + (lane & 15);
      int kr1 = kr0 + 32;
#pragma unroll
      for (int r = 0; r < 4; ++r) {
        As[kr0 * 33 + colb + r] = d0[r] + bk0;
        As[kr1 * 33 + colb + r] = d1[r] + bk1;
      }
    }
    __syncthreads();

    if (t < 32) {
      float m = -3.4e38f;
#pragma unroll
      for (int kk = 0; kk < 64; ++kk) m = fmaxf(m, As[kk * 33 + t]);
      Mf[t] = m;
    }
    __syncthreads();
    if (t < 128) {
      int col = t & 31, kg = t >> 5;
      float M = Mf[col], s = 0.f;
#pragma unroll
      for (int ii = 0; ii < 16; ++ii) {
        int a = (kg * 16 + ii) * 33 + col;
        float e = __expf(As[a] - M);
        As[a] = e;
        s += e;
      }
      sm4[kg * 32 + col] = s;
    }
    __syncthreads();

    {
      int k = t & 63, cg = t >> 6;
      union { u16 u[8]; short8 v; } cvt;
      float paks = 0.f;
#pragma unroll
      for (int j = 0; j < 8; ++j) {
        int col = cg * 8 + j;
        float inv = 1.f / (sm4[col] + sm4[32 + col] + sm4[64 + col] + sm4[96 + col]);
        float a = As[k * 33 + col] * inv;
        paks += a;
        cvt.u[j] = f2bf(a);
      }
      pak += paks;
      int dst = ((k >> 4) * 64 + (cg << 4) + (k & 15)) * 8;
      *(short8*)&afr[dst] = cvt.v;
    }
    __syncthreads();

    {
      short8 aa = *(short8*)&afr[(w * 64 + lane) * 8];
#pragma unroll
      for (int ct = 0; ct < 8; ++ct) {
        short8 xb = *(short8*)&xf[ct * 640 + (lane >> 4) * 160 + (lane & 15) * 8];
        pacc[ct] = __builtin_amdgcn_mfma_f32_16x16x32_bf16(aa, xb, pacc[ct], 0, 0, 0);
      }
    }
  }

  float* Pp = P + (size_t)(n * NCB + cb) * DDIM;
  {
    int krow = w * 16 + ((lane >> 4) << 2);
    int c0 = lane & 15;
#pragma unroll
    for (int ct = 0; ct < 8; ++ct)
#pragma unroll
      for (int r = 0; r < 4; ++r)
        Pp[(krow + r) * 128 + ct * 16 + c0] = pacc[ct][r];
  }
  pasum[t] = pak;
  __syncthreads();
  if (t < 64)
    PA[(size_t)(n * NCB + cb) * 64 + t] =
        pasum[t] + pasum[64 + t] + pasum[128 + t] + pasum[192 + t];
}

// ---------------------------------------------------------------------------
// K2: chunk-outer / window-inner. Block = (n, eb: 1024-e slice, wg: 5 windows).
// Reads 32-chunk span ONCE (P traffic 157 -> ~50 MB); 5 window accums/thread.
// Intra-norm per cluster (32 consecutive lanes); gss gets 8 partials/window.
// ---------------------------------------------------------------------------
__global__ __launch_bounds__(256) void k2_vlad(
    const float* __restrict__ P, const float* __restrict__ PA,
    const float* __restrict__ centers, u16* __restrict__ vlad16,
    float* __restrict__ gss)
{
  __shared__ float Ak[5][8];
  __shared__ float tsred[5][8];
  const int bx0 = blockIdx.x;                    // [0,384)
  const int id = (bx0 & 7) * 48 + (bx0 >> 3);    // XCD pin: n = bx0&7
  const int n = id / 48;
  const int rem = id - n * 48;
  const int eb = rem / 6, wg = rem - eb * 6;     // eb: 1024-e slice, wg: 5 windows
  const int t = threadIdx.x;

  // ---- windowed PA sums for 5 windows x 8 clusters of this slice ----
  if (t < 40) {
    int widx = t >> 3, cl = t & 7;
    int k = eb * 8 + cl;
    const float* pa = PA + (size_t)n * NCB * 64 + k;
    int a0 = 3 * (wg * 5 + widx) + 80;
    float s = 0.f;
#pragma unroll 4
    for (int i = 0; i < 20; ++i) {
      int cbk = a0 + i; cbk -= (cbk >= 90) ? 90 : 0; cbk -= (cbk >= 90) ? 90 : 0;
      s += pa[(size_t)cbk * 64];
    }
    Ak[widx][cl] = s;
  }
  __syncthreads();

  const int e0 = eb * 1024 + t * 4;
  float4 acc[5];
#pragma unroll
  for (int i = 0; i < 5; ++i) acc[i] = make_float4(0.f, 0.f, 0.f, 0.f);

  const int abase = 15 * wg + 80;                // first chunk of window wg*5
  const float* Pbase = P + (size_t)n * NCB * DDIM + e0;
  for (int j = 0; j < 32; ++j) {
    int cbk = abase + j; cbk -= (cbk >= 90) ? 90 : 0; cbk -= (cbk >= 90) ? 90 : 0;
    float4 u = *(const float4*)(Pbase + (size_t)cbk * DDIM);
    int lo = (j >= 20) ? (j - 17) / 3 : 0;
    int hi = (j / 3 < 4) ? j / 3 : 4;
    for (int widx = lo; widx <= hi; ++widx) {
      acc[widx].x += u.x; acc[widx].y += u.y; acc[widx].z += u.z; acc[widx].w += u.w;
    }
  }

  const float4 ce = *(const float4*)(centers + e0);
  const int cl = t >> 5;                         // cluster index within slice
#pragma unroll
  for (int widx = 0; widx < 5; ++widx) {
    float A = Ak[widx][cl];
    float v0 = acc[widx].x - ce.x * A;
    float v1 = acc[widx].y - ce.y * A;
    float v2 = acc[widx].z - ce.z * A;
    float v3 = acc[widx].w - ce.w * A;
    float ss4 = v0 * v0 + v1 * v1 + v2 * v2 + v3 * v3;
    float ssg = ss4;
    ssg += __shfl_xor(ssg, 1);
    ssg += __shfl_xor(ssg, 2);
    ssg += __shfl_xor(ssg, 4);
    ssg += __shfl_xor(ssg, 8);
    ssg += __shfl_xor(ssg, 16);                  // sum over the 32-lane cluster group
    float rn = 1.f / fmaxf(sqrtf(ssg), EPSF);
    if ((t & 31) == 0) tsred[widx][cl] = ssg * rn * rn;
    union { u16 u[4]; ushort2 s2[2]; } o;
    o.u[0] = f2bf(v0 * rn); o.u[1] = f2bf(v1 * rn);
    o.u[2] = f2bf(v2 * rn); o.u[3] = f2bf(v3 * rn);
    int win = n * NT + wg * 5 + widx;
    u16* vp = vlad16 + (size_t)win * DDIM + e0;
    *(ushort2*)vp = o.s2[0];
    *(ushort2*)(vp + 2) = o.s2[1];
  }
  __syncthreads();
  if (t < 5) {
    float s = 0.f;
#pragma unroll
    for (int c = 0; c < 8; ++c) s += tsred[t][c];
    int win = n * NT + wg * 5 + t;
    gss[(size_t)win * 8 + eb] = s;
  }
}

// ---------------------------------------------------------------------------
// K3 (MFMA): part[ks][240][256] = (vlad16 @ bf16(mlp_w)^T) * ga[r].
// mlp_w converted fp32->bf16 on the fly (L3-hot). ga sums 8 gss partials.
// ---------------------------------------------------------------------------
__global__ __launch_bounds__(256) void k3_gemm(
    const u16* __restrict__ vlad16, const float* __restrict__ gss,
    const float* __restrict__ mlp_w, float* __restrict__ part)
{
  __shared__ float ga[16];
  const int bx = blockIdx.x;
  const int rt = bx % 15;
  const int ks = bx / 15;          // 0..31, K-slice of 256
  const int t = threadIdx.x;
  const int lane = t & 63;
  const int w = t >> 6;

  if (t < 16) {
    int r = rt * 16 + t;
    float s = 0.f;
#pragma unroll
    for (int i = 0; i < 8; ++i) s += gss[(size_t)r * 8 + i];
    ga[t] = 1.f / fmaxf(sqrtf(s), EPSF);
  }
  __syncthreads();

  const int m = lane & 15;
  const int kg = lane >> 4;
  const int d0 = ks * 256 + kg * 8;
  const u16* arow = vlad16 + (size_t)(rt * 16 + m) * DDIM + d0;

  float4v acc[4];
#pragma unroll
  for (int i = 0; i < 4; ++i) acc[i] = (float4v){0.f, 0.f, 0.f, 0.f};

#pragma unroll
  for (int ko = 0; ko < 8; ++ko) {
    short8 a = *(const short8*)(arow + ko * 32);
#pragma unroll
    for (int nt = 0; nt < 4; ++nt) {
      int o = w * 64 + nt * 16 + m;
      const float* wrow = mlp_w + (size_t)o * DDIM + d0 + ko * 32;
      float4 u0 = *(const float4*)wrow;
      float4 u1 = *(const float4*)(wrow + 4);
      union { u16 u[8]; short8 v; } bb;
      bb.u[0] = f2bf(u0.x); bb.u[1] = f2bf(u0.y); bb.u[2] = f2bf(u0.z); bb.u[3] = f2bf(u0.w);
      bb.u[4] = f2bf(u1.x); bb.u[5] = f2bf(u1.y); bb.u[6] = f2bf(u1.z); bb.u[7] = f2bf(u1.w);
      acc[nt] = __builtin_amdgcn_mfma_f32_16x16x32_bf16(a, bb.v, acc[nt], 0, 0, 0);
    }
  }

  float g4[4];
#pragma unroll
  for (int r = 0; r < 4; ++r) g4[r] = ga[kg * 4 + r];
  float* pp = part + ((size_t)ks * 240 + rt * 16) * ODIM;
#pragma unroll
  for (int nt = 0; nt < 4; ++nt) {
    int o = w * 64 + nt * 16 + m;
#pragma unroll
    for (int r = 0; r < 4; ++r)
      pp[(kg * 4 + r) * ODIM + o] = acc[nt][r] * g4[r];
  }
}

// ---------------------------------------------------------------------------
// K4: sum 32 split-K partials + bias, row-normalize 240 x 256
// ---------------------------------------------------------------------------
__global__ __launch_bounds__(256) void k4_out(
    const float* __restrict__ part, const float* __restrict__ bias,
    float* __restrict__ out)
{
  __shared__ float red[4];
  const int r = blockIdx.x;
  const int o = threadIdx.x;
  float v = bias[o];
#pragma unroll
  for (int s = 0; s < 32; ++s) v += part[((size_t)s * 240 + r) * ODIM + o];
  float ss = v * v;
  ss += __shfl_xor(ss, 32);
  ss += __shfl_xor(ss, 16);
  ss += __shfl_xor(ss, 8);
  ss += __shfl_xor(ss, 4);
  ss += __shfl_xor(ss, 2);
  ss += __shfl_xor(ss, 1);
  if ((o & 63) == 0) red[o >> 6] = ss;
  __syncthreads();
  float total = red[0] + red[1] + red[2] + red[3];
  out[(size_t)r * ODIM + o] = v / fmaxf(sqrtf(total), EPSF);
}

// ---------------------------------------------------------------------------
extern "C" void kernel_launch(void* const* d_in, const int* in_sizes, int n_in,
                              void* d_out, int out_size, void* d_ws, size_t ws_size,
                              hipStream_t stream) {
  const float* x       = (const float*)d_in[0];
  const float* centers = (const float*)d_in[1];
  const float* conv_w  = (const float*)d_in[2];
  const float* conv_b  = (const float*)d_in[3];
  const float* mlp_w   = (const float*)d_in[4];
  const float* mlp_b   = (const float*)d_in[5];
  float* out = (float*)d_out;

  float* ws     = (float*)d_ws;
  float* P      = ws;                       // 5,898,240 floats (23.6 MB)
  float* PA     = ws + 5898240;             // 46,080 floats
  u16*   vlad16 = (u16*)(ws + 5944320);     // 240*8192 u16 (3.9 MB)
  float* gss    = (float*)(ws + 6927360);   // 240*8 floats
  float* part   = ws;                       // [32][240][256] overlays dead P

  k1_assign<<<dim3(8 * NCB),   dim3(256), 0, stream>>>(x, conv_w, conv_b, P, PA);
  k2_vlad  <<<dim3(8 * 8 * 6), dim3(256), 0, stream>>>(P, PA, centers, vlad16, gss);
  k3_gemm  <<<dim3(480),       dim3(256), 0, stream>>>(vlad16, gss, mlp_w, part);
  k4_out   <<<dim3(240),       dim3(256), 0, stream>>>(part, mlp_b, out);
}

// Round 9
// 175.646 us; speedup vs baseline: 1.2629x; 1.2629x over previous
//
#include <hip/hip_runtime.h>
#include <cstddef>

#define EPSF 1e-12f
#define NCB 90
#define NT 30
#define ODIM 256
#define DDIM 8192

typedef unsigned short u16;
typedef __attribute__((ext_vector_type(8))) short short8;
typedef __attribute__((ext_vector_type(4))) float float4v;

__device__ inline u16 f2bf(float f) {
  union { float f; unsigned u; } v; v.f = f;
  unsigned r = v.u + 0x7FFFu + ((v.u >> 16) & 1u);
  return (u16)(r >> 16);
}
__device__ inline float bf2f(u16 h) {
  union { unsigned u; float f; } v; v.u = ((unsigned)h) << 16;
  return v.f;
}

// ---------------------------------------------------------------------------
// K1 (MFMA): R8 structure but softmax is wave-local (cols [8w,8w+8) per wave,
// k-reduction via shfl_xor butterflies) fused with the a-frag build ->
// 4 barriers/cc instead of 6, no t<32/t<128 serial phases.
// ---------------------------------------------------------------------------
__global__ __launch_bounds__(256, 3) void k1_assign(
    const float* __restrict__ x,       // [8][128][16][900]
    const float* __restrict__ conv_w,  // [64][128]
    const float* __restrict__ conv_b,  // [64]
    float* __restrict__ P,             // [8][90][64][128]
    float* __restrict__ PA)            // [8][90][64]
{
  __shared__ u16 xtf[4160];        // logits A-frags: F*520 + lane*8 + j
  __shared__ u16 xf[5120];         // P B-frags: ct*640 + (lane>>4)*160 + (lane&15)*8 + j
  __shared__ float As[64 * 33];    // logits -> exp
  __shared__ u16 afr[2048];        // a frags
  __shared__ float invs[32];       // 1/sum per column
  __shared__ float pasum[256];

  const int bx0 = blockIdx.x;
  const int id = (bx0 & 7) * 90 + (bx0 >> 3);   // XCD pin: n = bx0&7
  const int n = id / NCB, cb = id - n * NCB;
  const int t = threadIdx.x;
  const int lane = t & 63;
  const int w = t >> 6;            // wave 0..3

  const float* xn = x + (size_t)n * 1843200 + cb * 10;

  const int colt = w & 1;
  const int kt0 = w >> 1;
  const float bk0 = conv_b[kt0 * 16 + (lane & 15)];
  const float bk1 = conv_b[(kt0 + 2) * 16 + (lane & 15)];

  short8 w0h[4], w0l[4], w1h[4], w1l[4];
  {
    int kr0 = kt0 * 16 + (lane & 15);
    int kr1 = kr0 + 32;
    int cbase = (lane >> 4) << 3;
#pragma unroll
    for (int cb32 = 0; cb32 < 4; ++cb32) {
      const float* wp0 = conv_w + (size_t)kr0 * 128 + cb32 * 32 + cbase;
      const float* wp1 = conv_w + (size_t)kr1 * 128 + cb32 * 32 + cbase;
      union { u16 u[8]; short8 v; } hh, ll;
#pragma unroll
      for (int j = 0; j < 8; ++j) {
        float fv = wp0[j];
        u16 h = f2bf(fv);
        hh.u[j] = h;
        ll.u[j] = f2bf(fv - bf2f(h));
      }
      w0h[cb32] = hh.v; w0l[cb32] = ll.v;
#pragma unroll
      for (int j = 0; j < 8; ++j) {
        float fv = wp1[j];
        u16 h = f2bf(fv);
        hh.u[j] = h;
        ll.u[j] = f2bf(fv - bf2f(h));
      }
      w1h[cb32] = hh.v; w1l[cb32] = ll.v;
    }
  }

  float4v pacc[8];
#pragma unroll
  for (int i = 0; i < 8; ++i) pacc[i] = (float4v){0.f, 0.f, 0.f, 0.f};
  float pak = 0.f;

  for (int cc = 0; cc < 5; ++cc) {
    __syncthreads();                     // prev P-mfma done before restaging
#pragma unroll
    for (int s = 0; s < 8; ++s) {
      int e2 = t + 256 * s;
      int c = e2 >> 4, p = e2 & 15;
      int cl = 2 * p;
      int g = cc * 32 + cl;
      int h = g / 10, wi = g - 10 * h;
      float2 val = *(const float2*)(xn + (size_t)c * 14400 + h * 900 + wi);
      u16 h0 = f2bf(val.x), h1 = f2bf(val.y);
      int ip = (c >> 4) * 640 + (p >> 2) * 160 + (c & 15) * 8 + (cl & 7);
      ushort2 pr; pr.x = h0; pr.y = h1;
      *(ushort2*)&xf[ip] = pr;
      int F = (p >> 3) * 4 + (c >> 5);
      int L = (((c >> 3) & 3) << 4) + (cl & 15);
      int i0 = F * 520 + L * 8 + (c & 7);
      xtf[i0] = h0;
      xtf[i0 + 8] = h1;
    }
    __syncthreads();

    // ---- logits MFMA ----
    {
      float4v d0 = (float4v){0.f, 0.f, 0.f, 0.f};
      float4v d1 = (float4v){0.f, 0.f, 0.f, 0.f};
#pragma unroll
      for (int cb32 = 0; cb32 < 4; ++cb32) {
        short8 xa = *(short8*)&xtf[(colt * 4 + cb32) * 520 + lane * 8];
        d0 = __builtin_amdgcn_mfma_f32_16x16x32_bf16(xa, w0h[cb32], d0, 0, 0, 0);
        d0 = __builtin_amdgcn_mfma_f32_16x16x32_bf16(xa, w0l[cb32], d0, 0, 0, 0);
        d1 = __builtin_amdgcn_mfma_f32_16x16x32_bf16(xa, w1h[cb32], d1, 0, 0, 0);
        d1 = __builtin_amdgcn_mfma_f32_16x16x32_bf16(xa, w1l[cb32], d1, 0, 0, 0);
      }
      int colb = colt * 16 + ((lane >> 4) << 2);
      int kr0 = kt0 * 16 + (lane & 15);
      int kr1 = kr0 + 32;
#pragma unroll
      for (int r = 0; r < 4; ++r) {
        As[kr0 * 33 + colb + r] = d0[r] + bk0;
        As[kr1 * 33 + colb + r] = d1[r] + bk1;
      }
    }
    __syncthreads();

    // ---- wave-local softmax over k for cols [8w, 8w+8) ----
    {
      const int col8 = lane & 7;
      const int kq = lane >> 3;
      const int colg = w * 8 + col8;
      float m = -3.4e38f;
#pragma unroll
      for (int i = 0; i < 8; ++i) m = fmaxf(m, As[(kq * 8 + i) * 33 + colg]);
      m = fmaxf(m, __shfl_xor(m, 8));
      m = fmaxf(m, __shfl_xor(m, 16));
      m = fmaxf(m, __shfl_xor(m, 32));
      float s = 0.f;
#pragma unroll
      for (int i = 0; i < 8; ++i) {
        int a = (kq * 8 + i) * 33 + colg;
        float e = __expf(As[a] - m);
        As[a] = e;
        s += e;
      }
      s += __shfl_xor(s, 8);
      s += __shfl_xor(s, 16);
      s += __shfl_xor(s, 32);
      if (kq == 0) invs[w * 8 + col8] = 1.f / s;
    }
    // ---- a-frag build: same wave reads the cols it just wrote (no barrier) ----
    {
      union { u16 u[8]; short8 v; } cvt;
      float paks = 0.f;
#pragma unroll
      for (int j = 0; j < 8; ++j) {
        float a = As[lane * 33 + w * 8 + j] * invs[w * 8 + j];
        paks += a;
        cvt.u[j] = f2bf(a);
      }
      pak += paks;
      int dst = ((lane >> 4) * 64 + (w << 4) + (lane & 15)) * 8;
      *(short8*)&afr[dst] = cvt.v;
    }
    __syncthreads();

    // ---- P MFMA: wave w owns kt = w; 8 c-tiles ----
    {
      short8 aa = *(short8*)&afr[(w * 64 + lane) * 8];
#pragma unroll
      for (int ct = 0; ct < 8; ++ct) {
        short8 xb = *(short8*)&xf[ct * 640 + (lane >> 4) * 160 + (lane & 15) * 8];
        pacc[ct] = __builtin_amdgcn_mfma_f32_16x16x32_bf16(aa, xb, pacc[ct], 0, 0, 0);
      }
    }
  }

  float* Pp = P + (size_t)(n * NCB + cb) * DDIM;
  {
    int krow = w * 16 + ((lane >> 4) << 2);
    int c0 = lane & 15;
#pragma unroll
    for (int ct = 0; ct < 8; ++ct)
#pragma unroll
      for (int r = 0; r < 4; ++r)
        Pp[(krow + r) * 128 + ct * 16 + c0] = pacc[ct][r];
  }
  pasum[t] = pak;
  __syncthreads();
  if (t < 64)
    PA[(size_t)(n * NCB + cb) * 64 + t] =
        pasum[t] + pasum[64 + t] + pasum[128 + t] + pasum[192 + t];
}

// ---------------------------------------------------------------------------
// K2: window-outer direct sums (R6 form, known good) + XCD pin; bf16 vlad out.
// ---------------------------------------------------------------------------
__global__ __launch_bounds__(256) void k2_vlad(
    const float* __restrict__ P, const float* __restrict__ PA,
    const float* __restrict__ centers, u16* __restrict__ vlad16,
    float* __restrict__ gss)
{
  __shared__ float Ak[16];
  __shared__ float red[4];
  const int bx0 = blockIdx.x;                    // [0,960)
  const int id = (bx0 & 7) * 120 + (bx0 >> 3);   // XCD pin: n = bx0&7
  const int n = id / 120;
  const int rem = id - n * 120;
  const int wt = rem >> 2, eb = rem & 3;
  const int win = n * NT + wt;
  const int t = threadIdx.x;

  if (t < 64) {
    int kk = t >> 2, ii = t & 3;
    float s = 0.f;
#pragma unroll
    for (int ss = 0; ss < 5; ++ss) {
      int i = ii + 4 * ss;
      int cb = (3 * wt + 80 + i) % 90;
      s += PA[((size_t)n * NCB + cb) * 64 + eb * 16 + kk];
    }
    s += __shfl_xor(s, 1);
    s += __shfl_xor(s, 2);
    if (ii == 0) Ak[kk] = s;
  }
  __syncthreads();

  const int e0 = eb * 2048 + t * 8;
  float v[8];
#pragma unroll
  for (int j = 0; j < 8; ++j) v[j] = 0.f;
#pragma unroll 5
  for (int i = 0; i < 20; ++i) {
    int cb = (3 * wt + 80 + i) % 90;
    const float* Pp = P + ((size_t)n * NCB + cb) * DDIM + e0;
    float4 u0 = *(const float4*)Pp;
    float4 u1 = *(const float4*)(Pp + 4);
    v[0] += u0.x; v[1] += u0.y; v[2] += u0.z; v[3] += u0.w;
    v[4] += u1.x; v[5] += u1.y; v[6] += u1.z; v[7] += u1.w;
  }
  const float A = Ak[t >> 4];
  const float* ce = centers + e0;
  float ss8 = 0.f;
#pragma unroll
  for (int j = 0; j < 8; ++j) {
    float val = v[j] - ce[j] * A;
    v[j] = val;
    ss8 += val * val;
  }
  float ssg = ss8;
  ssg += __shfl_xor(ssg, 1);
  ssg += __shfl_xor(ssg, 2);
  ssg += __shfl_xor(ssg, 4);
  ssg += __shfl_xor(ssg, 8);
  float rn = 1.f / fmaxf(sqrtf(ssg), EPSF);
  float ts = ss8 * rn * rn;
  ts += __shfl_xor(ts, 1);
  ts += __shfl_xor(ts, 2);
  ts += __shfl_xor(ts, 4);
  ts += __shfl_xor(ts, 8);
  ts += __shfl_xor(ts, 16);
  ts += __shfl_xor(ts, 32);
  if ((t & 63) == 0) red[t >> 6] = ts;
  __syncthreads();
  if (t == 0) gss[(size_t)win * 4 + eb] = red[0] + red[1] + red[2] + red[3];

  union { u16 u[8]; short8 s; } o;
#pragma unroll
  for (int j = 0; j < 8; ++j) o.u[j] = f2bf(v[j] * rn);
  *(short8*)(vlad16 + (size_t)win * DDIM + e0) = o.s;
}

// ---------------------------------------------------------------------------
// K3 (MFMA): part[ks][240][256] = (vlad16 @ bf16(mlp_w)^T) * ga[r].
// mlp_w converted fp32->bf16 on the fly; frags straight from global.
// ---------------------------------------------------------------------------
__global__ __launch_bounds__(256) void k3_gemm(
    const u16* __restrict__ vlad16, const float* __restrict__ gss,
    const float* __restrict__ mlp_w, float* __restrict__ part)
{
  __shared__ float ga[16];
  const int bx = blockIdx.x;
  const int rt = bx % 15;
  const int ks = bx / 15;          // 0..31, K-slice of 256
  const int t = threadIdx.x;
  const int lane = t & 63;
  const int w = t >> 6;

  if (t < 16) {
    int r = rt * 16 + t;
    float s = gss[r * 4] + gss[r * 4 + 1] + gss[r * 4 + 2] + gss[r * 4 + 3];
    ga[t] = 1.f / fmaxf(sqrtf(s), EPSF);
  }
  __syncthreads();

  const int m = lane & 15;
  const int kg = lane >> 4;
  const int d0 = ks * 256 + kg * 8;
  const u16* arow = vlad16 + (size_t)(rt * 16 + m) * DDIM + d0;

  float4v acc[4];
#pragma unroll
  for (int i = 0; i < 4; ++i) acc[i] = (float4v){0.f, 0.f, 0.f, 0.f};

#pragma unroll
  for (int ko = 0; ko < 8; ++ko) {
    short8 a = *(const short8*)(arow + ko * 32);
#pragma unroll
    for (int nt = 0; nt < 4; ++nt) {
      int o = w * 64 + nt * 16 + m;
      const float* wrow = mlp_w + (size_t)o * DDIM + d0 + ko * 32;
      float4 u0 = *(const float4*)wrow;
      float4 u1 = *(const float4*)(wrow + 4);
      union { u16 u[8]; short8 v; } bb;
      bb.u[0] = f2bf(u0.x); bb.u[1] = f2bf(u0.y); bb.u[2] = f2bf(u0.z); bb.u[3] = f2bf(u0.w);
      bb.u[4] = f2bf(u1.x); bb.u[5] = f2bf(u1.y); bb.u[6] = f2bf(u1.z); bb.u[7] = f2bf(u1.w);
      acc[nt] = __builtin_amdgcn_mfma_f32_16x16x32_bf16(a, bb.v, acc[nt], 0, 0, 0);
    }
  }

  float g4[4];
#pragma unroll
  for (int r = 0; r < 4; ++r) g4[r] = ga[kg * 4 + r];
  float* pp = part + ((size_t)ks * 240 + rt * 16) * ODIM;
#pragma unroll
  for (int nt = 0; nt < 4; ++nt) {
    int o = w * 64 + nt * 16 + m;
#pragma unroll
    for (int r = 0; r < 4; ++r)
      pp[(kg * 4 + r) * ODIM + o] = acc[nt][r] * g4[r];
  }
}

// ---------------------------------------------------------------------------
// K4: sum 32 split-K partials + bias, row-normalize 240 x 256
// ---------------------------------------------------------------------------
__global__ __launch_bounds__(256) void k4_out(
    const float* __restrict__ part, const float* __restrict__ bias,
    float* __restrict__ out)
{
  __shared__ float red[4];
  const int r = blockIdx.x;
  const int o = threadIdx.x;
  float v = bias[o];
#pragma unroll
  for (int s = 0; s < 32; ++s) v += part[((size_t)s * 240 + r) * ODIM + o];
  float ss = v * v;
  ss += __shfl_xor(ss, 32);
  ss += __shfl_xor(ss, 16);
  ss += __shfl_xor(ss, 8);
  ss += __shfl_xor(ss, 4);
  ss += __shfl_xor(ss, 2);
  ss += __shfl_xor(ss, 1);
  if ((o & 63) == 0) red[o >> 6] = ss;
  __syncthreads();
  float total = red[0] + red[1] + red[2] + red[3];
  out[(size_t)r * ODIM + o] = v / fmaxf(sqrtf(total), EPSF);
}

// ---------------------------------------------------------------------------
extern "C" void kernel_launch(void* const* d_in, const int* in_sizes, int n_in,
                              void* d_out, int out_size, void* d_ws, size_t ws_size,
                              hipStream_t stream) {
  const float* x       = (const float*)d_in[0];
  const float* centers = (const float*)d_in[1];
  const float* conv_w  = (const float*)d_in[2];
  const float* conv_b  = (const float*)d_in[3];
  const float* mlp_w   = (const float*)d_in[4];
  const float* mlp_b   = (const float*)d_in[5];
  float* out = (float*)d_out;

  float* ws     = (float*)d_ws;
  float* P      = ws;                       // 5,898,240 floats (23.6 MB)
  float* PA     = ws + 5898240;             // 46,080 floats
  u16*   vlad16 = (u16*)(ws + 5944320);     // 240*8192 u16 (3.9 MB)
  float* gss    = (float*)(ws + 6927360);   // 240*4 floats
  float* part   = ws;                       // [32][240][256] overlays dead P

  k1_assign<<<dim3(8 * NCB),    dim3(256), 0, stream>>>(x, conv_w, conv_b, P, PA);
  k2_vlad  <<<dim3(8 * NT * 4), dim3(256), 0, stream>>>(P, PA, centers, vlad16, gss);
  k3_gemm  <<<dim3(480),        dim3(256), 0, stream>>>(vlad16, gss, mlp_w, part);
  k4_out   <<<dim3(240),        dim3(256), 0, stream>>>(part, mlp_b, out);
}

// Round 10
// 172.585 us; speedup vs baseline: 1.2853x; 1.0177x over previous
//
#include <hip/hip_runtime.h>
#include <cstddef>

#define EPSF 1e-12f
#define NCB 90
#define NT 30
#define ODIM 256
#define DDIM 8192

typedef unsigned short u16;
typedef __attribute__((ext_vector_type(8))) short short8;
typedef __attribute__((ext_vector_type(4))) float float4v;

__device__ inline u16 f2bf(float f) {
  union { float f; unsigned u; } v; v.f = f;
  unsigned r = v.u + 0x7FFFu + ((v.u >> 16) & 1u);
  return (u16)(r >> 16);
}
__device__ inline float bf2f(u16 h) {
  union { unsigned u; float f; } v; v.u = ((unsigned)h) << 16;
  return v.f;
}

// ---------------------------------------------------------------------------
// K1 (MFMA): R9 structure + register-prefetch software pipeline: x for cc+1
// is loaded into 16 VGPRs after cc's LDS writes and consumed next iteration,
// so the staging barrier no longer exposes global-load latency.
// ---------------------------------------------------------------------------
__global__ __launch_bounds__(256, 3) void k1_assign(
    const float* __restrict__ x,       // [8][128][16][900]
    const float* __restrict__ conv_w,  // [64][128]
    const float* __restrict__ conv_b,  // [64]
    float* __restrict__ P,             // [8][90][64][128]
    float* __restrict__ PA)            // [8][90][64]
{
  __shared__ u16 xtf[4160];        // logits A-frags: F*520 + lane*8 + j
  __shared__ u16 xf[5120];         // P B-frags: ct*640 + (lane>>4)*160 + (lane&15)*8 + j
  __shared__ float As[64 * 33];    // logits -> exp
  __shared__ u16 afr[2048];        // a frags
  __shared__ float invs[32];       // 1/sum per column
  __shared__ float pasum[256];

  const int bx0 = blockIdx.x;
  const int id = (bx0 & 7) * 90 + (bx0 >> 3);   // XCD pin: n = bx0&7
  const int n = id / NCB, cb = id - n * NCB;
  const int t = threadIdx.x;
  const int lane = t & 63;
  const int w = t >> 6;            // wave 0..3

  const float* xn = x + (size_t)n * 1843200 + cb * 10;

  const int colt = w & 1;
  const int kt0 = w >> 1;
  const float bk0 = conv_b[kt0 * 16 + (lane & 15)];
  const float bk1 = conv_b[(kt0 + 2) * 16 + (lane & 15)];

  short8 w0h[4], w0l[4], w1h[4], w1l[4];
  {
    int kr0 = kt0 * 16 + (lane & 15);
    int kr1 = kr0 + 32;
    int cbase = (lane >> 4) << 3;
#pragma unroll
    for (int cb32 = 0; cb32 < 4; ++cb32) {
      const float* wp0 = conv_w + (size_t)kr0 * 128 + cb32 * 32 + cbase;
      const float* wp1 = conv_w + (size_t)kr1 * 128 + cb32 * 32 + cbase;
      union { u16 u[8]; short8 v; } hh, ll;
#pragma unroll
      for (int j = 0; j < 8; ++j) {
        float fv = wp0[j];
        u16 h = f2bf(fv);
        hh.u[j] = h;
        ll.u[j] = f2bf(fv - bf2f(h));
      }
      w0h[cb32] = hh.v; w0l[cb32] = ll.v;
#pragma unroll
      for (int j = 0; j < 8; ++j) {
        float fv = wp1[j];
        u16 h = f2bf(fv);
        hh.u[j] = h;
        ll.u[j] = f2bf(fv - bf2f(h));
      }
      w1h[cb32] = hh.v; w1l[cb32] = ll.v;
    }
  }

  float4v pacc[8];
#pragma unroll
  for (int i = 0; i < 8; ++i) pacc[i] = (float4v){0.f, 0.f, 0.f, 0.f};
  float pak = 0.f;

  // ---- prologue: load cc=0 x into registers ----
  float2 xr[8];
#pragma unroll
  for (int s = 0; s < 8; ++s) {
    int e2 = t + 256 * s;
    int c = e2 >> 4, p = e2 & 15;
    int cl = 2 * p;
    int h = cl / 10, wi = cl - 10 * h;
    xr[s] = *(const float2*)(xn + (size_t)c * 14400 + h * 900 + wi);
  }

  for (int cc = 0; cc < 5; ++cc) {
    __syncthreads();                     // prev P-mfma done before restaging
    // ---- write prefetched regs to both LDS layouts ----
#pragma unroll
    for (int s = 0; s < 8; ++s) {
      int e2 = t + 256 * s;
      int c = e2 >> 4, p = e2 & 15;
      int cl = 2 * p;
      u16 h0 = f2bf(xr[s].x), h1 = f2bf(xr[s].y);
      int ip = (c >> 4) * 640 + (p >> 2) * 160 + (c & 15) * 8 + (cl & 7);
      ushort2 pr; pr.x = h0; pr.y = h1;
      *(ushort2*)&xf[ip] = pr;
      int F = (p >> 3) * 4 + (c >> 5);
      int L = (((c >> 3) & 3) << 4) + (cl & 15);
      int i0 = F * 520 + L * 8 + (c & 7);
      xtf[i0] = h0;
      xtf[i0 + 8] = h1;
    }
    // ---- issue next cc's loads; they retire behind this cc's compute ----
    if (cc < 4) {
#pragma unroll
      for (int s = 0; s < 8; ++s) {
        int e2 = t + 256 * s;
        int c = e2 >> 4, p = e2 & 15;
        int g = (cc + 1) * 32 + 2 * p;
        int h = g / 10, wi = g - 10 * h;
        xr[s] = *(const float2*)(xn + (size_t)c * 14400 + h * 900 + wi);
      }
    }
    __syncthreads();

    // ---- logits MFMA ----
    {
      float4v d0 = (float4v){0.f, 0.f, 0.f, 0.f};
      float4v d1 = (float4v){0.f, 0.f, 0.f, 0.f};
#pragma unroll
      for (int cb32 = 0; cb32 < 4; ++cb32) {
        short8 xa = *(short8*)&xtf[(colt * 4 + cb32) * 520 + lane * 8];
        d0 = __builtin_amdgcn_mfma_f32_16x16x32_bf16(xa, w0h[cb32], d0, 0, 0, 0);
        d0 = __builtin_amdgcn_mfma_f32_16x16x32_bf16(xa, w0l[cb32], d0, 0, 0, 0);
        d1 = __builtin_amdgcn_mfma_f32_16x16x32_bf16(xa, w1h[cb32], d1, 0, 0, 0);
        d1 = __builtin_amdgcn_mfma_f32_16x16x32_bf16(xa, w1l[cb32], d1, 0, 0, 0);
      }
      int colb = colt * 16 + ((lane >> 4) << 2);
      int kr0 = kt0 * 16 + (lane & 15);
      int kr1 = kr0 + 32;
#pragma unroll
      for (int r = 0; r < 4; ++r) {
        As[kr0 * 33 + colb + r] = d0[r] + bk0;
        As[kr1 * 33 + colb + r] = d1[r] + bk1;
      }
    }
    __syncthreads();

    // ---- wave-local softmax over k for cols [8w, 8w+8) ----
    {
      const int col8 = lane & 7;
      const int kq = lane >> 3;
      const int colg = w * 8 + col8;
      float m = -3.4e38f;
#pragma unroll
      for (int i = 0; i < 8; ++i) m = fmaxf(m, As[(kq * 8 + i) * 33 + colg]);
      m = fmaxf(m, __shfl_xor(m, 8));
      m = fmaxf(m, __shfl_xor(m, 16));
      m = fmaxf(m, __shfl_xor(m, 32));
      float s = 0.f;
#pragma unroll
      for (int i = 0; i < 8; ++i) {
        int a = (kq * 8 + i) * 33 + colg;
        float e = __expf(As[a] - m);
        As[a] = e;
        s += e;
      }
      s += __shfl_xor(s, 8);
      s += __shfl_xor(s, 16);
      s += __shfl_xor(s, 32);
      if (kq == 0) invs[w * 8 + col8] = 1.f / s;
    }
    // ---- a-frag build (same wave, no barrier needed) ----
    {
      union { u16 u[8]; short8 v; } cvt;
      float paks = 0.f;
#pragma unroll
      for (int j = 0; j < 8; ++j) {
        float a = As[lane * 33 + w * 8 + j] * invs[w * 8 + j];
        paks += a;
        cvt.u[j] = f2bf(a);
      }
      pak += paks;
      int dst = ((lane >> 4) * 64 + (w << 4) + (lane & 15)) * 8;
      *(short8*)&afr[dst] = cvt.v;
    }
    __syncthreads();

    // ---- P MFMA: wave w owns kt = w; 8 c-tiles ----
    {
      short8 aa = *(short8*)&afr[(w * 64 + lane) * 8];
#pragma unroll
      for (int ct = 0; ct < 8; ++ct) {
        short8 xb = *(short8*)&xf[ct * 640 + (lane >> 4) * 160 + (lane & 15) * 8];
        pacc[ct] = __builtin_amdgcn_mfma_f32_16x16x32_bf16(aa, xb, pacc[ct], 0, 0, 0);
      }
    }
  }

  float* Pp = P + (size_t)(n * NCB + cb) * DDIM;
  {
    int krow = w * 16 + ((lane >> 4) << 2);
    int c0 = lane & 15;
#pragma unroll
    for (int ct = 0; ct < 8; ++ct)
#pragma unroll
      for (int r = 0; r < 4; ++r)
        Pp[(krow + r) * 128 + ct * 16 + c0] = pacc[ct][r];
  }
  pasum[t] = pak;
  __syncthreads();
  if (t < 64)
    PA[(size_t)(n * NCB + cb) * 64 + t] =
        pasum[t] + pasum[64 + t] + pasum[128 + t] + pasum[192 + t];
}

// ---------------------------------------------------------------------------
// K2: window-outer direct sums + XCD pin; bf16 vlad out. (R9 form, unchanged)
// ---------------------------------------------------------------------------
__global__ __launch_bounds__(256) void k2_vlad(
    const float* __restrict__ P, const float* __restrict__ PA,
    const float* __restrict__ centers, u16* __restrict__ vlad16,
    float* __restrict__ gss)
{
  __shared__ float Ak[16];
  __shared__ float red[4];
  const int bx0 = blockIdx.x;                    // [0,960)
  const int id = (bx0 & 7) * 120 + (bx0 >> 3);   // XCD pin: n = bx0&7
  const int n = id / 120;
  const int rem = id - n * 120;
  const int wt = rem >> 2, eb = rem & 3;
  const int win = n * NT + wt;
  const int t = threadIdx.x;

  if (t < 64) {
    int kk = t >> 2, ii = t & 3;
    float s = 0.f;
#pragma unroll
    for (int ss = 0; ss < 5; ++ss) {
      int i = ii + 4 * ss;
      int cb = (3 * wt + 80 + i) % 90;
      s += PA[((size_t)n * NCB + cb) * 64 + eb * 16 + kk];
    }
    s += __shfl_xor(s, 1);
    s += __shfl_xor(s, 2);
    if (ii == 0) Ak[kk] = s;
  }
  __syncthreads();

  const int e0 = eb * 2048 + t * 8;
  float v[8];
#pragma unroll
  for (int j = 0; j < 8; ++j) v[j] = 0.f;
#pragma unroll 5
  for (int i = 0; i < 20; ++i) {
    int cb = (3 * wt + 80 + i) % 90;
    const float* Pp = P + ((size_t)n * NCB + cb) * DDIM + e0;
    float4 u0 = *(const float4*)Pp;
    float4 u1 = *(const float4*)(Pp + 4);
    v[0] += u0.x; v[1] += u0.y; v[2] += u0.z; v[3] += u0.w;
    v[4] += u1.x; v[5] += u1.y; v[6] += u1.z; v[7] += u1.w;
  }
  const float A = Ak[t >> 4];
  const float* ce = centers + e0;
  float ss8 = 0.f;
#pragma unroll
  for (int j = 0; j < 8; ++j) {
    float val = v[j] - ce[j] * A;
    v[j] = val;
    ss8 += val * val;
  }
  float ssg = ss8;
  ssg += __shfl_xor(ssg, 1);
  ssg += __shfl_xor(ssg, 2);
  ssg += __shfl_xor(ssg, 4);
  ssg += __shfl_xor(ssg, 8);
  float rn = 1.f / fmaxf(sqrtf(ssg), EPSF);
  float ts = ss8 * rn * rn;
  ts += __shfl_xor(ts, 1);
  ts += __shfl_xor(ts, 2);
  ts += __shfl_xor(ts, 4);
  ts += __shfl_xor(ts, 8);
  ts += __shfl_xor(ts, 16);
  ts += __shfl_xor(ts, 32);
  if ((t & 63) == 0) red[t >> 6] = ts;
  __syncthreads();
  if (t == 0) gss[(size_t)win * 4 + eb] = red[0] + red[1] + red[2] + red[3];

  union { u16 u[8]; short8 s; } o;
#pragma unroll
  for (int j = 0; j < 8; ++j) o.u[j] = f2bf(v[j] * rn);
  *(short8*)(vlad16 + (size_t)win * DDIM + e0) = o.s;
}

// ---------------------------------------------------------------------------
// K3 (MFMA): grid 960 (o split x2 -> 3.75 blocks/CU for the latency-chained
// K-loop). part[ks][240][256] = (vlad16 @ bf16(mlp_w)^T) * ga[r].
// ---------------------------------------------------------------------------
__global__ __launch_bounds__(256) void k3_gemm(
    const u16* __restrict__ vlad16, const float* __restrict__ gss,
    const float* __restrict__ mlp_w, float* __restrict__ part)
{
  __shared__ float ga[16];
  const int bx = blockIdx.x;
  const int rt = bx % 15;
  const int h = bx / 15;           // [0,64)
  const int ot = h & 1;            // o half
  const int ks = h >> 1;           // 0..31, K-slice of 256
  const int t = threadIdx.x;
  const int lane = t & 63;
  const int w = t >> 6;

  if (t < 16) {
    int r = rt * 16 + t;
    float s = gss[r * 4] + gss[r * 4 + 1] + gss[r * 4 + 2] + gss[r * 4 + 3];
    ga[t] = 1.f / fmaxf(sqrtf(s), EPSF);
  }
  __syncthreads();

  const int m = lane & 15;
  const int kg = lane >> 4;
  const int d0 = ks * 256 + kg * 8;
  const u16* arow = vlad16 + (size_t)(rt * 16 + m) * DDIM + d0;

  float4v acc[2];
#pragma unroll
  for (int i = 0; i < 2; ++i) acc[i] = (float4v){0.f, 0.f, 0.f, 0.f};

#pragma unroll
  for (int ko = 0; ko < 8; ++ko) {
    short8 a = *(const short8*)(arow + ko * 32);
#pragma unroll
    for (int nt = 0; nt < 2; ++nt) {
      int o = ot * 128 + w * 32 + nt * 16 + m;
      const float* wrow = mlp_w + (size_t)o * DDIM + d0 + ko * 32;
      float4 u0 = *(const float4*)wrow;
      float4 u1 = *(const float4*)(wrow + 4);
      union { u16 u[8]; short8 v; } bb;
      bb.u[0] = f2bf(u0.x); bb.u[1] = f2bf(u0.y); bb.u[2] = f2bf(u0.z); bb.u[3] = f2bf(u0.w);
      bb.u[4] = f2bf(u1.x); bb.u[5] = f2bf(u1.y); bb.u[6] = f2bf(u1.z); bb.u[7] = f2bf(u1.w);
      acc[nt] = __builtin_amdgcn_mfma_f32_16x16x32_bf16(a, bb.v, acc[nt], 0, 0, 0);
    }
  }

  float g4[4];
#pragma unroll
  for (int r = 0; r < 4; ++r) g4[r] = ga[kg * 4 + r];
  float* pp = part + ((size_t)ks * 240 + rt * 16) * ODIM;
#pragma unroll
  for (int nt = 0; nt < 2; ++nt) {
    int o = ot * 128 + w * 32 + nt * 16 + m;
#pragma unroll
    for (int r = 0; r < 4; ++r)
      pp[(kg * 4 + r) * ODIM + o] = acc[nt][r] * g4[r];
  }
}

// ---------------------------------------------------------------------------
// K4: sum 32 split-K partials + bias, row-normalize 240 x 256
// ---------------------------------------------------------------------------
__global__ __launch_bounds__(256) void k4_out(
    const float* __restrict__ part, const float* __restrict__ bias,
    float* __restrict__ out)
{
  __shared__ float red[4];
  const int r = blockIdx.x;
  const int o = threadIdx.x;
  float v = bias[o];
#pragma unroll
  for (int s = 0; s < 32; ++s) v += part[((size_t)s * 240 + r) * ODIM + o];
  float ss = v * v;
  ss += __shfl_xor(ss, 32);
  ss += __shfl_xor(ss, 16);
  ss += __shfl_xor(ss, 8);
  ss += __shfl_xor(ss, 4);
  ss += __shfl_xor(ss, 2);
  ss += __shfl_xor(ss, 1);
  if ((o & 63) == 0) red[o >> 6] = ss;
  __syncthreads();
  float total = red[0] + red[1] + red[2] + red[3];
  out[(size_t)r * ODIM + o] = v / fmaxf(sqrtf(total), EPSF);
}

// ---------------------------------------------------------------------------
extern "C" void kernel_launch(void* const* d_in, const int* in_sizes, int n_in,
                              void* d_out, int out_size, void* d_ws, size_t ws_size,
                              hipStream_t stream) {
  const float* x       = (const float*)d_in[0];
  const float* centers = (const float*)d_in[1];
  const float* conv_w  = (const float*)d_in[2];
  const float* conv_b  = (const float*)d_in[3];
  const float* mlp_w   = (const float*)d_in[4];
  const float* mlp_b   = (const float*)d_in[5];
  float* out = (float*)d_out;

  float* ws     = (float*)d_ws;
  float* P      = ws;                       // 5,898,240 floats (23.6 MB)
  float* PA     = ws + 5898240;             // 46,080 floats
  u16*   vlad16 = (u16*)(ws + 5944320);     // 240*8192 u16 (3.9 MB)
  float* gss    = (float*)(ws + 6927360);   // 240*4 floats
  float* part   = ws;                       // [32][240][256] overlays dead P

  k1_assign<<<dim3(8 * NCB),    dim3(256), 0, stream>>>(x, conv_w, conv_b, P, PA);
  k2_vlad  <<<dim3(8 * NT * 4), dim3(256), 0, stream>>>(P, PA, centers, vlad16, gss);
  k3_gemm  <<<dim3(960),        dim3(256), 0, stream>>>(vlad16, gss, mlp_w, part);
  k4_out   <<<dim3(240),        dim3(256), 0, stream>>>(part, mlp_b, out);
}